// Round 11
// baseline (38.101 us; speedup 1.0000x reference)
//
#include <hip/hip_runtime.h>
#include <math.h>

#define QN 8192
#define AN 2048
#define DN 64
#define NSPLIT 32
#define CHUNK 64        // atoms per block in mfma_splat
#define AH 136          // halfs per atom in packed M (17 float4)
#define NQ 2            // q-tiles of 16 per wave

#define SQ2f      1.4142135623730951f
#define INV_SQ2f  0.7071067811865476f
#define SQ6_INVf  0.4082482904638631f
#define SQ2_3f    0.816496580927726f
#define LOG2Ef    1.4426950408889634f

typedef __attribute__((ext_vector_type(8))) _Float16 half8;
typedef __attribute__((ext_vector_type(4))) float f32x4;

__device__ __forceinline__ float wave_sum(float v) {
#pragma unroll
  for (int off = 32; off > 0; off >>= 1) v += __shfl_xor(v, off, 64);
  return v;
}

__device__ __forceinline__ unsigned pkh(float a, float b) {
  auto h = __builtin_amdgcn_cvt_pkrtz(a, b);   // __fp16 ext_vector(2)
  return __builtin_bit_cast(unsigned, h);
}

// ---------------- Kernel A: per-atom precompute + pack (proven round 9/10) --
__global__ __launch_bounds__(256) void precompute_pack(
    const float* __restrict__ atom_coords, const float* __restrict__ alpha,
    const float* __restrict__ even_scalar, const float* __restrict__ odd_scalar,
    const float* __restrict__ odd_vector, const float* __restrict__ even_vector,
    const float* __restrict__ even_tensor, const float* __restrict__ odd_tensor,
    const float* __restrict__ W, const float* __restrict__ b,
    _Float16* __restrict__ Mh, float4* __restrict__ atomC)
{
  const int a = blockIdx.x * 4 + (threadIdx.x >> 6);
  const int d = threadIdx.x & 63;

  const float es  = even_scalar[a * DN + d];
  const float os  = odd_scalar[a * DN + d];
  const float ov0 = odd_vector[(a * DN + d) * 3 + 0];
  const float ov1 = odd_vector[(a * DN + d) * 3 + 1];
  const float ov2 = odd_vector[(a * DN + d) * 3 + 2];
  const float ev0 = even_vector[(a * DN + d) * 3 + 0];
  const float ev1 = even_vector[(a * DN + d) * 3 + 1];
  const float ev2 = even_vector[(a * DN + d) * 3 + 2];
  const float et0 = even_tensor[(a * DN + d) * 5 + 0];
  const float et1 = even_tensor[(a * DN + d) * 5 + 1];
  const float et2 = even_tensor[(a * DN + d) * 5 + 2];
  const float et3 = even_tensor[(a * DN + d) * 5 + 3];
  const float et4 = even_tensor[(a * DN + d) * 5 + 4];
  const float ot0 = odd_tensor[(a * DN + d) * 5 + 0];
  const float ot1 = odd_tensor[(a * DN + d) * 5 + 1];
  const float ot2 = odd_tensor[(a * DN + d) * 5 + 2];
  const float ot3 = odd_tensor[(a * DN + d) * 5 + 3];
  const float ot4 = odd_tensor[(a * DN + d) * 5 + 4];

  const float w0 = W[0 * DN + d];
  const float w1 = W[1 * DN + d];
  const float w2 = W[2 * DN + d];
  const float w3 = W[3 * DN + d];
  const float w4 = W[4 * DN + d];
  const float w5 = W[5 * DN + d];
  const float w6 = W[6 * DN + d];
  const float w7 = W[7 * DN + d];
  const float w8 = W[8 * DN + d];
  const float w9 = W[9 * DN + d];

  float r[34];
  r[0]  = es * w0;
  r[1]  = os * w1;
  r[2]  = ov0 * w2; r[3]  = ov1 * w2; r[4]  = ov2 * w2;
  r[5]  = ev0 * w3; r[6]  = ev1 * w3; r[7]  = ev2 * w3;
  r[8]  = et0 * w4; r[9]  = et1 * w4; r[10] = et2 * w4; r[11] = et3 * w4; r[12] = et4 * w4;
  r[13] = ot0 * w5; r[14] = ot1 * w5; r[15] = ot2 * w5; r[16] = ot3 * w5; r[17] = ot4 * w5;
  r[18] = ov0 * w6; r[19] = ov1 * w6; r[20] = ov2 * w6;
  r[21] = ev0 * w7; r[22] = ev1 * w7; r[23] = ev2 * w7;
  r[24] = et0 * w8; r[25] = et1 * w8; r[26] = et2 * w8; r[27] = et3 * w8; r[28] = et4 * w8;
  r[29] = ot0 * w9; r[30] = ot1 * w9; r[31] = ot2 * w9; r[32] = ot3 * w9; r[33] = ot4 * w9;

#pragma unroll
  for (int k = 0; k < 34; ++k) r[k] = wave_sum(r[k]);

  if (d < 16) {
    const float eb = b[4];
    const float ec0 = r[8] + eb, ec1 = r[9] + eb, ec2 = r[10] + eb,
                ec3 = r[11] + eb, ec4 = r[12] + eb;
    const float Qzz = ec1 * SQ2_3f;
    const float Qxx = 0.5f * (ec0 * SQ2f - Qzz);
    const float Qyy = 0.5f * (-ec0 * SQ2f - Qzz);
    const float Qxy = ec2 * INV_SQ2f, Qxz = ec3 * INV_SQ2f, Qyz = ec4 * INV_SQ2f;
    const float ob = b[5];
    const float oc0 = r[13] + ob, oc1 = r[14] + ob, oc2 = r[15] + ob,
                oc3 = r[16] + ob, oc4 = r[17] + ob;
    const float Ozz = oc1 * SQ2_3f;
    const float Oxx = 0.5f * (oc0 * SQ2f - Ozz);
    const float Oyy = 0.5f * (-oc0 * SQ2f - Ozz);
    const float Oxy = oc2 * INV_SQ2f, Oxz = oc3 * INV_SQ2f, Oyz = oc4 * INV_SQ2f;
    const float A0e = r[24] * INV_SQ2f, A1e = r[25] * SQ6_INVf;
    const float A2e = r[26] * SQ2f, A3e = r[27] * SQ2f, A4e = r[28] * SQ2f;
    const float qe_xx = A0e - A1e, qe_yy = -A0e - A1e, qe_zz = 2.0f * A1e;
    const float A0o = r[29] * INV_SQ2f, A1o = r[30] * SQ6_INVf;
    const float A2o = r[31] * SQ2f, A3o = r[32] * SQ2f, A4o = r[33] * SQ2f;
    const float qo_xx = A0o - A1o, qo_yy = -A0o - A1o, qo_zz = 2.0f * A1o;

    float m[8];
#pragma unroll
    for (int k = 0; k < 8; ++k) m[k] = 0.f;
    switch (d) {
      case 0:  m[0] = 1.f; break;
      case 1:  m[0] = r[0] + b[0]; break;
      case 2:  m[0] = r[1] + b[1]; break;
      case 3:  m[0]=r[2]+b[2]; m[1]=Qxx; m[2]=Qxy; m[3]=Qxz; break;
      case 4:  m[0]=r[3]+b[2]; m[1]=Qxy; m[2]=Qyy; m[3]=Qyz; break;
      case 5:  m[0]=r[4]+b[2]; m[1]=Qxz; m[2]=Qyz; m[3]=Qzz; break;
      case 6:  m[0]=r[5]+b[3]; m[1]=Oxx; m[2]=Oxy; m[3]=Oxz; break;
      case 7:  m[0]=r[6]+b[3]; m[1]=Oxy; m[2]=Oyy; m[3]=Oyz; break;
      case 8:  m[0]=r[7]+b[3]; m[1]=Oxz; m[2]=Oyz; m[3]=Ozz; break;
      case 9:  m[0]=qe_zz; m[1]=r[18]; m[2]=r[19]; m[3]=r[20]; break;
      case 10: m[0]=qo_zz; m[1]=r[21]; m[2]=r[22]; m[3]=r[23]; break;
      case 12: m[0]=qe_xx-qe_zz; m[1]=qe_yy-qe_zz;
               m[2]=A2e; m[3]=A3e; m[4]=A4e; break;
      case 13: m[0]=qo_xx-qo_zz; m[1]=qo_yy-qo_zz;
               m[2]=A2o; m[3]=A3o; m[4]=A4o; break;
      default: break;   // rows 11, 14, 15 stay zero
    }
    union { unsigned u[4]; half8 h; } row;
    row.u[0] = pkh(m[0], m[1]);
    row.u[1] = pkh(m[2], m[3]);
    row.u[2] = pkh(m[4], m[5]);
    row.u[3] = pkh(m[6], m[7]);
    *(half8*)(Mh + (size_t)a * AH + d * 8) = row.h;
  } else if (d == 16) {
    atomC[a] = make_float4(atom_coords[a * 3 + 0], atom_coords[a * 3 + 1],
                           atom_coords[a * 3 + 2], -alpha[a] * LOG2Ef);
  }
}

// ---------------- Kernel B: MFMA splat, NQ=2, plain P stores ----------------
// Per wave: 32 queries (2 q-tiles of 16) x 16 fields; grid (64, 32) = 2048
// blocks. MFMA body proven (rounds 7-10); epilogue = round-9 P stores.
__global__ __launch_bounds__(256, 6) void mfma_splat(
    const float* __restrict__ qcoord, const _Float16* __restrict__ Mh,
    const float4* __restrict__ atomC, float* __restrict__ P)
{
  __shared__ __align__(16) _Float16 smM[CHUNK * AH];
  __shared__ float4 smC[CHUNK];
  const int tid = threadIdx.x;
  const int abase = blockIdx.y * CHUNK;

  {
    const float4* src = (const float4*)(Mh + (size_t)abase * AH);
    float4* dst = (float4*)smM;
#pragma unroll
    for (int t = 0; t < 4; ++t) dst[tid + t * 256] = src[tid + t * 256];
    if (tid < 64) dst[1024 + tid] = src[1024 + tid];
  }
  if (tid < CHUNK) smC[tid] = atomC[abase + tid];

  const int lane = tid & 63;
  const int wid = tid >> 6;
  const int fq = lane & 15;
  const int g = (lane >> 4) & 3;
  const int qb = blockIdx.x * 128 + wid * 32;

  float qx[NQ], qy[NQ], qz[NQ];
#pragma unroll
  for (int jt = 0; jt < NQ; ++jt) {
    const int q = qb + jt * 16 + fq;
    qx[jt] = qcoord[q * 3 + 0];
    qy[jt] = qcoord[q * 3 + 1];
    qz[jt] = qcoord[q * 3 + 2];
  }

  const int a1off = (fq < 11 ? fq : 11) * 8;
  const int a2off = 96 + (fq == 9 ? 0 : (fq == 10 ? 8 : 16));
  const _Float16* p1 = smM + g * AH + a1off;
  const _Float16* p2 = smM + g * AH + a2off;

  __syncthreads();

  f32x4 acc[NQ];
#pragma unroll
  for (int jt = 0; jt < NQ; ++jt) acc[jt] = (f32x4){0.f, 0.f, 0.f, 0.f};

  for (int it = 0; it < CHUNK / 4; ++it) {
    const half8 a1 = *(const half8*)(p1 + it * (4 * AH));
    const half8 a2 = *(const half8*)(p2 + it * (4 * AH));
    const float4 ca = smC[it * 4 + g];

#pragma unroll
    for (int jt = 0; jt < NQ; ++jt) {
      const float dx = qx[jt] - ca.x, dy = qy[jt] - ca.y, dz = qz[jt] - ca.z;
      const float d2 = fmaf(dx, dx, fmaf(dy, dy, dz * dz));
      const float w = __builtin_amdgcn_exp2f(ca.w * d2);
      const float inv = __builtin_amdgcn_rsqf(d2);
      const float ux = dx * inv, uy = dy * inv, uz = dz * inv;
      const float m1 = w * ux, m2 = w * uy, m3 = w * uz;
      const float m4 = m1 * ux, m6 = m1 * uy, m7 = m1 * uz;
      const float m5 = m2 * uy, m8 = m2 * uz;

      union { unsigned uu[4]; half8 h; } b1, b2;
      b1.uu[0] = pkh(w, m1);   b1.uu[1] = pkh(m2, m3);
      b1.uu[2] = 0u;           b1.uu[3] = 0u;
      b2.uu[0] = pkh(m4, m5);  b2.uu[1] = pkh(m6, m7);
      b2.uu[2] = pkh(m8, 0.f); b2.uu[3] = 0u;

      acc[jt] = __builtin_amdgcn_mfma_f32_16x16x32_f16(a1, b1.h, acc[jt], 0, 0, 0);
      acc[jt] = __builtin_amdgcn_mfma_f32_16x16x32_f16(a2, b2.h, acc[jt], 0, 0, 0);
    }
  }

  const int frow = (lane >> 4) * 4;
#pragma unroll
  for (int jt = 0; jt < NQ; ++jt) {
    const int q = qb + jt * 16 + fq;
    float* Pb = P + (size_t)blockIdx.y * 16 * QN + q;
#pragma unroll
    for (int r = 0; r < 4; ++r) {
      const int f = frow + r;
      if (f < 11) Pb[(size_t)f * QN] = acc[jt][r];
    }
  }
}

// ---------------- Kernel C: split-parallel reduce + finalize (proven r9) ----
__global__ __launch_bounds__(256) void reduce_combine(
    const float* __restrict__ P, const float* __restrict__ b,
    float* __restrict__ out)
{
  __shared__ float sm[11][8][32];
  const int tid = threadIdx.x;
  const int ql = tid & 31;
  const int sg = tid >> 5;            // 0..7
  const int q = blockIdx.x * 32 + ql;

  float acc[11];
#pragma unroll
  for (int f = 0; f < 11; ++f) acc[f] = 0.f;
#pragma unroll
  for (int j = 0; j < 4; ++j) {
    const int s = sg * 4 + j;
    const float* Ps = P + (size_t)s * 16 * QN + q;
#pragma unroll
    for (int f = 0; f < 11; ++f) acc[f] += Ps[(size_t)f * QN];
  }
#pragma unroll
  for (int f = 0; f < 11; ++f) sm[f][sg][ql] = acc[f];
  __syncthreads();

  if (tid < 32) {
    float a[11];
#pragma unroll
    for (int f = 0; f < 11; ++f) {
      float v = 0.f;
#pragma unroll
      for (int s = 0; s < 8; ++s) v += sm[f][s][tid];
      a[f] = v;
    }
    const int qq = blockIdx.x * 32 + tid;
    const float b_ea = b[6] + b[8];
    const float b_oa = b[7] + b[9];

    const float Sw = fmaxf(a[0], 1e-8f);
    const float inv = 1.0f / Sw;
    const float snw = a[0] * inv;
    const float scal = a[1] * inv;
    const float pse  = a[2] * inv;
    const float vx = a[3] * inv;
    const float vy = a[4] * inv;
    const float vz = a[5] * inv;
    const float bx = a[6] * inv;
    const float by = a[7] * inv;
    const float bz = a[8] * inv;
    const float ea = fmaf(b_ea, snw, a[9] * inv);
    const float oa = fmaf(b_oa, snw, a[10] * inv);

    const float evenc = scal + ea;
    const float oddc  = pse + oa;
    const float vn = sqrtf(fmaf(vx, vx, fmaf(vy, vy, vz * vz)));
    const float bn = sqrtf(fmaf(bx, bx, fmaf(by, by, bz * bz)));
    const float total = evenc + oddc + 0.1f * vn + 0.05f * bn;

    out[qq] = total;
    out[QN + qq] = evenc;
    out[2 * QN + qq] = oddc;
    float* mv = out + 3 * QN + (size_t)qq * 16;
    mv[0] = scal;
    mv[1] = vx; mv[2] = vy; mv[3] = vz;
    mv[4] = 0.f;
    mv[5] = bz; mv[6] = -by; mv[7] = bx;
    mv[8] = 0.f; mv[9] = 0.f; mv[10] = 0.f;
    mv[11] = pse;
    mv[12] = 0.f; mv[13] = 0.f; mv[14] = 0.f; mv[15] = 0.f;
  }
}

extern "C" void kernel_launch(void* const* d_in, const int* in_sizes, int n_in,
                              void* d_out, int out_size, void* d_ws, size_t ws_size,
                              hipStream_t stream) {
  const float* query_coords = (const float*)d_in[0];
  const float* atom_coords  = (const float*)d_in[1];
  const float* alpha        = (const float*)d_in[2];
  const float* even_scalar  = (const float*)d_in[3];
  const float* odd_scalar   = (const float*)d_in[4];
  const float* odd_vector   = (const float*)d_in[5];
  const float* even_vector  = (const float*)d_in[6];
  const float* even_tensor  = (const float*)d_in[7];
  const float* odd_tensor   = (const float*)d_in[8];
  const float* W            = (const float*)d_in[9];
  const float* b            = (const float*)d_in[10];
  float* out = (float*)d_out;

  const size_t mhBytes = (size_t)AN * AH * sizeof(_Float16);        // 557056
  char* ws = (char*)d_ws;
  _Float16*  Mh     = (_Float16*)ws;
  float4*    atomCp = (float4*)(ws + mhBytes);
  float*     P      = (float*)(ws + mhBytes + (size_t)AN * sizeof(float4));

  precompute_pack<<<AN / 4, 256, 0, stream>>>(
      atom_coords, alpha, even_scalar, odd_scalar, odd_vector, even_vector,
      even_tensor, odd_tensor, W, b, Mh, atomCp);
  mfma_splat<<<dim3(QN / 128, NSPLIT), 256, 0, stream>>>(
      query_coords, Mh, atomCp, P);
  reduce_combine<<<QN / 32, 256, 0, stream>>>(P, b, out);
}

// Round 12
// 30.630 us; speedup vs baseline: 1.2439x; 1.2439x over previous
//
#include <hip/hip_runtime.h>
#include <math.h>

#define QN 8192
#define AN 2048
#define DN 64
#define NSPLIT 32
#define CHUNK 64        // atoms per block in mfma_splat
#define AH 136          // halfs per atom in packed M (17 float4)
#define NQ 2            // q-tiles of 16 per wave

#define SQ2f      1.4142135623730951f
#define INV_SQ2f  0.7071067811865476f
#define SQ6_INVf  0.4082482904638631f
#define SQ2_3f    0.816496580927726f
#define LOG2Ef    1.4426950408889634f

typedef __attribute__((ext_vector_type(8))) _Float16 half8;
typedef __attribute__((ext_vector_type(4))) float f32x4;

__device__ __forceinline__ float wave_sum(float v) {
#pragma unroll
  for (int off = 32; off > 0; off >>= 1) v += __shfl_xor(v, off, 64);
  return v;
}

__device__ __forceinline__ unsigned pkh(float a, float b) {
  auto h = __builtin_amdgcn_cvt_pkrtz(a, b);   // __fp16 ext_vector(2)
  return __builtin_bit_cast(unsigned, h);
}

// ---------------- Kernel A: per-atom precompute + pack + Acc zeroing --------
// (proven round 10)
__global__ __launch_bounds__(256) void precompute_pack(
    const float* __restrict__ atom_coords, const float* __restrict__ alpha,
    const float* __restrict__ even_scalar, const float* __restrict__ odd_scalar,
    const float* __restrict__ odd_vector, const float* __restrict__ even_vector,
    const float* __restrict__ even_tensor, const float* __restrict__ odd_tensor,
    const float* __restrict__ W, const float* __restrict__ b,
    _Float16* __restrict__ Mh, float4* __restrict__ atomC,
    float* __restrict__ Acc)
{
  // zero the atomic accumulator (512 blocks x 256 threads >= 11*QN)
  {
    const int zi = blockIdx.x * 256 + threadIdx.x;
    if (zi < 11 * QN) Acc[zi] = 0.f;
  }

  const int a = blockIdx.x * 4 + (threadIdx.x >> 6);
  const int d = threadIdx.x & 63;

  const float es  = even_scalar[a * DN + d];
  const float os  = odd_scalar[a * DN + d];
  const float ov0 = odd_vector[(a * DN + d) * 3 + 0];
  const float ov1 = odd_vector[(a * DN + d) * 3 + 1];
  const float ov2 = odd_vector[(a * DN + d) * 3 + 2];
  const float ev0 = even_vector[(a * DN + d) * 3 + 0];
  const float ev1 = even_vector[(a * DN + d) * 3 + 1];
  const float ev2 = even_vector[(a * DN + d) * 3 + 2];
  const float et0 = even_tensor[(a * DN + d) * 5 + 0];
  const float et1 = even_tensor[(a * DN + d) * 5 + 1];
  const float et2 = even_tensor[(a * DN + d) * 5 + 2];
  const float et3 = even_tensor[(a * DN + d) * 5 + 3];
  const float et4 = even_tensor[(a * DN + d) * 5 + 4];
  const float ot0 = odd_tensor[(a * DN + d) * 5 + 0];
  const float ot1 = odd_tensor[(a * DN + d) * 5 + 1];
  const float ot2 = odd_tensor[(a * DN + d) * 5 + 2];
  const float ot3 = odd_tensor[(a * DN + d) * 5 + 3];
  const float ot4 = odd_tensor[(a * DN + d) * 5 + 4];

  const float w0 = W[0 * DN + d];
  const float w1 = W[1 * DN + d];
  const float w2 = W[2 * DN + d];
  const float w3 = W[3 * DN + d];
  const float w4 = W[4 * DN + d];
  const float w5 = W[5 * DN + d];
  const float w6 = W[6 * DN + d];
  const float w7 = W[7 * DN + d];
  const float w8 = W[8 * DN + d];
  const float w9 = W[9 * DN + d];

  float r[34];
  r[0]  = es * w0;
  r[1]  = os * w1;
  r[2]  = ov0 * w2; r[3]  = ov1 * w2; r[4]  = ov2 * w2;
  r[5]  = ev0 * w3; r[6]  = ev1 * w3; r[7]  = ev2 * w3;
  r[8]  = et0 * w4; r[9]  = et1 * w4; r[10] = et2 * w4; r[11] = et3 * w4; r[12] = et4 * w4;
  r[13] = ot0 * w5; r[14] = ot1 * w5; r[15] = ot2 * w5; r[16] = ot3 * w5; r[17] = ot4 * w5;
  r[18] = ov0 * w6; r[19] = ov1 * w6; r[20] = ov2 * w6;
  r[21] = ev0 * w7; r[22] = ev1 * w7; r[23] = ev2 * w7;
  r[24] = et0 * w8; r[25] = et1 * w8; r[26] = et2 * w8; r[27] = et3 * w8; r[28] = et4 * w8;
  r[29] = ot0 * w9; r[30] = ot1 * w9; r[31] = ot2 * w9; r[32] = ot3 * w9; r[33] = ot4 * w9;

#pragma unroll
  for (int k = 0; k < 34; ++k) r[k] = wave_sum(r[k]);

  if (d < 16) {
    const float eb = b[4];
    const float ec0 = r[8] + eb, ec1 = r[9] + eb, ec2 = r[10] + eb,
                ec3 = r[11] + eb, ec4 = r[12] + eb;
    const float Qzz = ec1 * SQ2_3f;
    const float Qxx = 0.5f * (ec0 * SQ2f - Qzz);
    const float Qyy = 0.5f * (-ec0 * SQ2f - Qzz);
    const float Qxy = ec2 * INV_SQ2f, Qxz = ec3 * INV_SQ2f, Qyz = ec4 * INV_SQ2f;
    const float ob = b[5];
    const float oc0 = r[13] + ob, oc1 = r[14] + ob, oc2 = r[15] + ob,
                oc3 = r[16] + ob, oc4 = r[17] + ob;
    const float Ozz = oc1 * SQ2_3f;
    const float Oxx = 0.5f * (oc0 * SQ2f - Ozz);
    const float Oyy = 0.5f * (-oc0 * SQ2f - Ozz);
    const float Oxy = oc2 * INV_SQ2f, Oxz = oc3 * INV_SQ2f, Oyz = oc4 * INV_SQ2f;
    const float A0e = r[24] * INV_SQ2f, A1e = r[25] * SQ6_INVf;
    const float A2e = r[26] * SQ2f, A3e = r[27] * SQ2f, A4e = r[28] * SQ2f;
    const float qe_xx = A0e - A1e, qe_yy = -A0e - A1e, qe_zz = 2.0f * A1e;
    const float A0o = r[29] * INV_SQ2f, A1o = r[30] * SQ6_INVf;
    const float A2o = r[31] * SQ2f, A3o = r[32] * SQ2f, A4o = r[33] * SQ2f;
    const float qo_xx = A0o - A1o, qo_yy = -A0o - A1o, qo_zz = 2.0f * A1o;

    float m[8];
#pragma unroll
    for (int k = 0; k < 8; ++k) m[k] = 0.f;
    switch (d) {
      case 0:  m[0] = 1.f; break;
      case 1:  m[0] = r[0] + b[0]; break;
      case 2:  m[0] = r[1] + b[1]; break;
      case 3:  m[0]=r[2]+b[2]; m[1]=Qxx; m[2]=Qxy; m[3]=Qxz; break;
      case 4:  m[0]=r[3]+b[2]; m[1]=Qxy; m[2]=Qyy; m[3]=Qyz; break;
      case 5:  m[0]=r[4]+b[2]; m[1]=Qxz; m[2]=Qyz; m[3]=Qzz; break;
      case 6:  m[0]=r[5]+b[3]; m[1]=Oxx; m[2]=Oxy; m[3]=Oxz; break;
      case 7:  m[0]=r[6]+b[3]; m[1]=Oxy; m[2]=Oyy; m[3]=Oyz; break;
      case 8:  m[0]=r[7]+b[3]; m[1]=Oxz; m[2]=Oyz; m[3]=Ozz; break;
      case 9:  m[0]=qe_zz; m[1]=r[18]; m[2]=r[19]; m[3]=r[20]; break;
      case 10: m[0]=qo_zz; m[1]=r[21]; m[2]=r[22]; m[3]=r[23]; break;
      case 12: m[0]=qe_xx-qe_zz; m[1]=qe_yy-qe_zz;
               m[2]=A2e; m[3]=A3e; m[4]=A4e; break;
      case 13: m[0]=qo_xx-qo_zz; m[1]=qo_yy-qo_zz;
               m[2]=A2o; m[3]=A3o; m[4]=A4o; break;
      default: break;   // rows 11, 14, 15 stay zero
    }
    union { unsigned u[4]; half8 h; } row;
    row.u[0] = pkh(m[0], m[1]);
    row.u[1] = pkh(m[2], m[3]);
    row.u[2] = pkh(m[4], m[5]);
    row.u[3] = pkh(m[6], m[7]);
    *(half8*)(Mh + (size_t)a * AH + d * 8) = row.h;
  } else if (d == 16) {
    atomC[a] = make_float4(atom_coords[a * 3 + 0], atom_coords[a * 3 + 1],
                           atom_coords[a * 3 + 2], -alpha[a] * LOG2Ef);
  }
}

// ---------------- Kernel B: MFMA splat, NQ=2, atomic accumulate -------------
// Round-10 structure; launch_bounds min-waves 6->8 to cap VGPR at 64 and
// reach 8 waves/SIMD; ux-form monomials (round-11-proven, shorter dep chain).
__global__ __launch_bounds__(256, 8) void mfma_splat(
    const float* __restrict__ qcoord, const _Float16* __restrict__ Mh,
    const float4* __restrict__ atomC, float* __restrict__ Acc)
{
  __shared__ __align__(16) _Float16 smM[CHUNK * AH];
  __shared__ float4 smC[CHUNK];
  const int tid = threadIdx.x;
  const int abase = blockIdx.y * CHUNK;

  {
    const float4* src = (const float4*)(Mh + (size_t)abase * AH);
    float4* dst = (float4*)smM;
#pragma unroll
    for (int t = 0; t < 4; ++t) dst[tid + t * 256] = src[tid + t * 256];
    if (tid < 64) dst[1024 + tid] = src[1024 + tid];
  }
  if (tid < CHUNK) smC[tid] = atomC[abase + tid];

  const int lane = tid & 63;
  const int wid = tid >> 6;
  const int fq = lane & 15;
  const int g = (lane >> 4) & 3;
  const int qb = blockIdx.x * 128 + wid * 32;

  float qx[NQ], qy[NQ], qz[NQ];
#pragma unroll
  for (int jt = 0; jt < NQ; ++jt) {
    const int q = qb + jt * 16 + fq;
    qx[jt] = qcoord[q * 3 + 0];
    qy[jt] = qcoord[q * 3 + 1];
    qz[jt] = qcoord[q * 3 + 2];
  }

  const int a1off = (fq < 11 ? fq : 11) * 8;
  const int a2off = 96 + (fq == 9 ? 0 : (fq == 10 ? 8 : 16));
  const _Float16* p1 = smM + g * AH + a1off;
  const _Float16* p2 = smM + g * AH + a2off;

  __syncthreads();

  f32x4 acc[NQ];
#pragma unroll
  for (int jt = 0; jt < NQ; ++jt) acc[jt] = (f32x4){0.f, 0.f, 0.f, 0.f};

  for (int it = 0; it < CHUNK / 4; ++it) {
    const half8 a1 = *(const half8*)(p1 + it * (4 * AH));
    const half8 a2 = *(const half8*)(p2 + it * (4 * AH));
    const float4 ca = smC[it * 4 + g];

#pragma unroll
    for (int jt = 0; jt < NQ; ++jt) {
      const float dx = qx[jt] - ca.x, dy = qy[jt] - ca.y, dz = qz[jt] - ca.z;
      const float d2 = fmaf(dx, dx, fmaf(dy, dy, dz * dz));
      const float w = __builtin_amdgcn_exp2f(ca.w * d2);
      const float inv = __builtin_amdgcn_rsqf(d2);
      const float ux = dx * inv, uy = dy * inv, uz = dz * inv;
      const float m1 = w * ux, m2 = w * uy, m3 = w * uz;
      const float m4 = m1 * ux, m6 = m1 * uy, m7 = m1 * uz;
      const float m5 = m2 * uy, m8 = m2 * uz;

      union { unsigned uu[4]; half8 h; } b1, b2;
      b1.uu[0] = pkh(w, m1);   b1.uu[1] = pkh(m2, m3);
      b1.uu[2] = 0u;           b1.uu[3] = 0u;
      b2.uu[0] = pkh(m4, m5);  b2.uu[1] = pkh(m6, m7);
      b2.uu[2] = pkh(m8, 0.f); b2.uu[3] = 0u;

      acc[jt] = __builtin_amdgcn_mfma_f32_16x16x32_f16(a1, b1.h, acc[jt], 0, 0, 0);
      acc[jt] = __builtin_amdgcn_mfma_f32_16x16x32_f16(a2, b2.h, acc[jt], 0, 0, 0);
    }
  }

  const int frow = (lane >> 4) * 4;
#pragma unroll
  for (int jt = 0; jt < NQ; ++jt) {
    const int q = qb + jt * 16 + fq;
#pragma unroll
    for (int r = 0; r < 4; ++r) {
      const int f = frow + r;
      if (f < 11) atomicAdd(&Acc[(size_t)f * QN + q], acc[jt][r]);
    }
  }
}

// ---------------- Kernel C: finalize from Acc[11][QN] (proven round 10) -----
__global__ __launch_bounds__(256) void finalize(
    const float* __restrict__ Acc, const float* __restrict__ b,
    float* __restrict__ out)
{
  const int q = blockIdx.x * 256 + threadIdx.x;
  float a[11];
#pragma unroll
  for (int f = 0; f < 11; ++f) a[f] = Acc[(size_t)f * QN + q];

  const float b_ea = b[6] + b[8];
  const float b_oa = b[7] + b[9];

  const float Sw = fmaxf(a[0], 1e-8f);
  const float inv = 1.0f / Sw;
  const float snw = a[0] * inv;
  const float scal = a[1] * inv;
  const float pse  = a[2] * inv;
  const float vx = a[3] * inv;
  const float vy = a[4] * inv;
  const float vz = a[5] * inv;
  const float bx = a[6] * inv;
  const float by = a[7] * inv;
  const float bz = a[8] * inv;
  const float ea = fmaf(b_ea, snw, a[9] * inv);
  const float oa = fmaf(b_oa, snw, a[10] * inv);

  const float evenc = scal + ea;
  const float oddc  = pse + oa;
  const float vn = sqrtf(fmaf(vx, vx, fmaf(vy, vy, vz * vz)));
  const float bn = sqrtf(fmaf(bx, bx, fmaf(by, by, bz * bz)));
  const float total = evenc + oddc + 0.1f * vn + 0.05f * bn;

  out[q] = total;
  out[QN + q] = evenc;
  out[2 * QN + q] = oddc;
  float* mv = out + 3 * QN + (size_t)q * 16;
  mv[0] = scal;
  mv[1] = vx; mv[2] = vy; mv[3] = vz;
  mv[4] = 0.f;
  mv[5] = bz; mv[6] = -by; mv[7] = bx;
  mv[8] = 0.f; mv[9] = 0.f; mv[10] = 0.f;
  mv[11] = pse;
  mv[12] = 0.f; mv[13] = 0.f; mv[14] = 0.f; mv[15] = 0.f;
}

extern "C" void kernel_launch(void* const* d_in, const int* in_sizes, int n_in,
                              void* d_out, int out_size, void* d_ws, size_t ws_size,
                              hipStream_t stream) {
  const float* query_coords = (const float*)d_in[0];
  const float* atom_coords  = (const float*)d_in[1];
  const float* alpha        = (const float*)d_in[2];
  const float* even_scalar  = (const float*)d_in[3];
  const float* odd_scalar   = (const float*)d_in[4];
  const float* odd_vector   = (const float*)d_in[5];
  const float* even_vector  = (const float*)d_in[6];
  const float* even_tensor  = (const float*)d_in[7];
  const float* odd_tensor   = (const float*)d_in[8];
  const float* W            = (const float*)d_in[9];
  const float* b            = (const float*)d_in[10];
  float* out = (float*)d_out;

  const size_t mhBytes = (size_t)AN * AH * sizeof(_Float16);        // 557056
  char* ws = (char*)d_ws;
  _Float16*  Mh     = (_Float16*)ws;
  float4*    atomCp = (float4*)(ws + mhBytes);
  float*     Acc    = (float*)(ws + mhBytes + (size_t)AN * sizeof(float4));

  precompute_pack<<<AN / 4, 256, 0, stream>>>(
      atom_coords, alpha, even_scalar, odd_scalar, odd_vector, even_vector,
      even_tensor, odd_tensor, W, b, Mh, atomCp, Acc);
  mfma_splat<<<dim3(QN / 128, NSPLIT), 256, 0, stream>>>(
      query_coords, Mh, atomCp, Acc);
  finalize<<<QN / 256, 256, 0, stream>>>(Acc, b, out);
}